// Round 10
// baseline (177.703 us; speedup 1.0000x reference)
//
#include <hip/hip_runtime.h>
#include <math.h>

#define TOKS 16384
#define CDIM 128
#define NH 4
#define HD 32
#define HID 512
#define QSCALE 0.17677669529663687f
#define LEPS 1e-5f

typedef const float* fp;
typedef const unsigned short* bfp16;
typedef __attribute__((ext_vector_type(8))) short bf16x8;
typedef __attribute__((ext_vector_type(4))) float f32x4;

__device__ inline unsigned int bfp2(float a, float b) {
    unsigned int ua = __float_as_uint(a); ua = (ua + 0x7FFFu + ((ua >> 16) & 1u)) >> 16;
    unsigned int ub = __float_as_uint(b); ub = (ub + 0x7FFFu + ((ub >> 16) & 1u)) >> 16;
    return ua | (ub << 16);
}
__device__ inline unsigned short bf1(float a) {
    unsigned int u = __float_as_uint(a);
    return (unsigned short)((u + 0x7FFFu + ((u >> 16) & 1u)) >> 16);
}
__device__ inline float lo16(unsigned int u) { return __uint_as_float(u << 16); }
__device__ inline float hi16(unsigned int u) { return __uint_as_float(u & 0xFFFF0000u); }

// ---------------- prep: weight convert+transpose ONLY (768 blocks) ----------------
__global__ __launch_bounds__(256) void prep(fp qw, fp pw, fp f1w, fp f2w,
                                            unsigned short* __restrict__ wt) {
    int e = blockIdx.x * 256 + threadIdx.x;
    float v;
    if (e < 49152)       { int n = e >> 7,  k = e & 127;          v = qw[(size_t)k * 384 + n]; }
    else if (e < 65536)  { int i = e - 49152;  int n = i >> 7, k = i & 127; v = pw[(size_t)k * 128 + n]; }
    else if (e < 131072) { int i = e - 65536;  int n = i >> 7, k = i & 127; v = f1w[(size_t)k * 512 + n]; }
    else                 { int i = e - 131072; int n = i >> 9, k = i & 511; v = f2w[(size_t)k * 128 + n]; }
    wt[e] = bf1(v);
}

// ---------------- k1: fused LN1(x) + QKV GEMM (K=128, N=384); Q->f32, K/V->bf16 ------
__global__ __launch_bounds__(256) void k1_mfma(fp x, fp g1, fp b1, bfp16 wt0, fp wb,
                                               float* __restrict__ qb,
                                               unsigned short* __restrict__ kvb) {
    __shared__ unsigned int lds[12288];
    const int m0 = blockIdx.x * 128;
    const int nb = blockIdx.y * 64;
    const int tid = threadIdx.x;
#pragma unroll
    for (int i = 0; i < 8; i++) {
        int slot = tid + i * 256;
        int m = slot >> 4, c16 = slot & 15;
        const float4 v0 = *(const float4*)(x + (size_t)(m0 + m) * CDIM + c16 * 8);
        const float4 v1 = *(const float4*)(x + (size_t)(m0 + m) * CDIM + c16 * 8 + 4);
        float s = v0.x + v0.y + v0.z + v0.w + v1.x + v1.y + v1.z + v1.w;
        float q = v0.x * v0.x + v0.y * v0.y + v0.z * v0.z + v0.w * v0.w
                + v1.x * v1.x + v1.y * v1.y + v1.z * v1.z + v1.w * v1.w;
#pragma unroll
        for (int mm = 8; mm >= 1; mm >>= 1) { s += __shfl_xor(s, mm); q += __shfl_xor(q, mm); }
        float mu = s * (1.f / 128.f);
        float rs = rsqrtf(q * (1.f / 128.f) - mu * mu + LEPS);
        const float4 ga = *(const float4*)(g1 + c16 * 8);
        const float4 gb = *(const float4*)(g1 + c16 * 8 + 4);
        const float4 ba = *(const float4*)(b1 + c16 * 8);
        const float4 bb = *(const float4*)(b1 + c16 * 8 + 4);
        uint4 o;
        o.x = bfp2((v0.x - mu) * rs * ga.x + ba.x, (v0.y - mu) * rs * ga.y + ba.y);
        o.y = bfp2((v0.z - mu) * rs * ga.z + ba.z, (v0.w - mu) * rs * ga.w + ba.w);
        o.z = bfp2((v1.x - mu) * rs * gb.x + bb.x, (v1.y - mu) * rs * gb.y + bb.y);
        o.w = bfp2((v1.z - mu) * rs * gb.z + bb.z, (v1.w - mu) * rs * gb.w + bb.w);
        *(uint4*)&lds[m * 64 + ((c16 ^ (m & 15)) << 2)] = o;
    }
#pragma unroll
    for (int i = 0; i < 4; i++) {
        int slot = tid + i * 256;
        int n = slot >> 4, c16 = slot & 15;
        const uint4 v4 = *(const uint4*)(wt0 + (size_t)(nb + n) * 128 + c16 * 8);
        *(uint4*)&lds[8192 + n * 64 + (c16 ^ (n & 15)) * 4] = v4;
    }
    __syncthreads();

    const int lane = tid & 63, wid = tid >> 6, quad = lane >> 4, l16 = lane & 15;
    f32x4 acc[2][4];
#pragma unroll
    for (int mt = 0; mt < 2; mt++)
#pragma unroll
        for (int nt = 0; nt < 4; nt++) acc[mt][nt] = (f32x4){0.f, 0.f, 0.f, 0.f};
#pragma unroll
    for (int kk = 0; kk < 4; kk++) {
        int c = kk * 4 + quad;
        bf16x8 a0 = *(bf16x8*)&lds[(wid * 32 + l16) * 64 + (c ^ l16) * 4];
        bf16x8 a1 = *(bf16x8*)&lds[(wid * 32 + 16 + l16) * 64 + (c ^ l16) * 4];
#pragma unroll
        for (int nt = 0; nt < 4; nt++) {
            bf16x8 bf = *(bf16x8*)&lds[8192 + (nt * 16 + l16) * 64 + (c ^ l16) * 4];
            acc[0][nt] = __builtin_amdgcn_mfma_f32_16x16x32_bf16(a0, bf, acc[0][nt], 0, 0, 0);
            acc[1][nt] = __builtin_amdgcn_mfma_f32_16x16x32_bf16(a1, bf, acc[1][nt], 0, 0, 0);
        }
    }
#pragma unroll
    for (int nt = 0; nt < 4; nt++) {
        int col = nb + nt * 16 + l16;
        float bias = wb[col];
#pragma unroll
        for (int mt = 0; mt < 2; mt++)
#pragma unroll
            for (int r = 0; r < 4; r++) {
                int row = m0 + wid * 32 + mt * 16 + quad * 4 + r;
                float vres = acc[mt][nt][r] + bias;
                if (col < 128)
                    qb[(size_t)row * 128 + col] = vres * QSCALE;
                else if (col < 256)
                    kvb[(size_t)row * 256 + (col - 128)] = bf1(vres);
                else
                    kvb[(size_t)row * 256 + 128 + (col - 256)] = bf1(vres);
            }
    }
}

// ---------------- k2: tiled neighborhood attention (R6-verified version) ----------
__global__ __launch_bounds__(512) void k2_attn(const float* __restrict__ qb,
                                               const unsigned short* __restrict__ kvb,
                                               fp rpb, unsigned short* __restrict__ attnb) {
    __shared__ unsigned int lds[25088];          // 196 rows x 128 uints (K 64 | V 64)
    const int tile = blockIdx.x;                 // 256 tiles
    const int bb = tile >> 6;
    const int ty0 = ((tile >> 3) & 7) << 3;
    const int tx0 = (tile & 7) << 3;
    const int ry0 = min(max(ty0 - 3, 0), 50);
    const int rx0 = min(max(tx0 - 3, 0), 50);
    const int tid = threadIdx.x;

#pragma unroll
    for (int it = 0; it < 13; it++) {
        int slot = it * 512 + tid;
        if (slot < 6272) {
            int r = slot >> 5, c = slot & 31;
            int i = r / 14, j = r - i * 14;
            const uint4 v = *(const uint4*)(kvb + (size_t)((bb << 12) + (ry0 + i) * 64 + rx0 + j) * 256 + c * 8);
            *(uint4*)&lds[r * 128 + ((c ^ (r & 7)) << 2)] = v;
        }
    }

    const int dh = tid & 1;
    const int head = (tid >> 1) & 3;
    const int t = tid >> 3;
    const int tx = t & 7, ty = t >> 3;
    const int y = ty0 + ty, x = tx0 + tx;
    const int token = (bb << 12) + y * 64 + x;
    const int sy = min(max(y - 3, 0), 57);
    const int sx = min(max(x - 3, 0), 57);
    const int ib = sy - ry0, jb = sx - rx0;
    const float* rp = rpb + head * 169 + (sy - y + 6) * 13 + (sx - x + 6);

    float q[16];
    {
        const float4* qp = (const float4*)(qb + (size_t)token * 128 + head * 32 + dh * 16);
        float4 a = qp[0], b = qp[1], c = qp[2], d = qp[3];
        q[0] = a.x; q[1] = a.y; q[2] = a.z; q[3] = a.w;
        q[4] = b.x; q[5] = b.y; q[6] = b.z; q[7] = b.w;
        q[8] = c.x; q[9] = c.y; q[10] = c.z; q[11] = c.w;
        q[12] = d.x; q[13] = d.y; q[14] = d.z; q[15] = d.w;
    }
    __syncthreads();

    const int cb = (head << 2) + (dh << 1);
    float m = -1e30f, l = 0.f;
    float o[16];
#pragma unroll
    for (int i2 = 0; i2 < 16; i2++) o[i2] = 0.f;

    for (int dy = 0; dy < 7; dy++) {
        float s[7];
#pragma unroll
        for (int dx = 0; dx < 7; dx++) {
            int r = (ib + dy) * 14 + jb + dx;
            int sw = r & 7;
            const uint4 k0 = *(const uint4*)&lds[r * 128 + ((cb ^ sw) << 2)];
            const uint4 k1 = *(const uint4*)&lds[r * 128 + (((cb + 1) ^ sw) << 2)];
            float ss = q[0] * lo16(k0.x) + q[1] * hi16(k0.x)
                     + q[2] * lo16(k0.y) + q[3] * hi16(k0.y)
                     + q[4] * lo16(k0.z) + q[5] * hi16(k0.z)
                     + q[6] * lo16(k0.w) + q[7] * hi16(k0.w)
                     + q[8] * lo16(k1.x) + q[9] * hi16(k1.x)
                     + q[10] * lo16(k1.y) + q[11] * hi16(k1.y)
                     + q[12] * lo16(k1.z) + q[13] * hi16(k1.z)
                     + q[14] * lo16(k1.w) + q[15] * hi16(k1.w);
            ss += __shfl_xor(ss, 1);
            s[dx] = ss + rp[dy * 13 + dx];
        }
        float rm = s[0];
#pragma unroll
        for (int dx = 1; dx < 7; dx++) rm = fmaxf(rm, s[dx]);
        float mn = fmaxf(m, rm);
        float cf = __expf(m - mn);
        l *= cf;
#pragma unroll
        for (int i2 = 0; i2 < 16; i2++) o[i2] *= cf;
#pragma unroll
        for (int dx = 0; dx < 7; dx++) {
            int r = (ib + dy) * 14 + jb + dx;
            int sw = r & 7;
            const uint4 v0 = *(const uint4*)&lds[r * 128 + (((cb + 16) ^ sw) << 2)];
            const uint4 v1 = *(const uint4*)&lds[r * 128 + (((cb + 17) ^ sw) << 2)];
            float p = __expf(s[dx] - mn);
            l += p;
            o[0] += p * lo16(v0.x); o[1] += p * hi16(v0.x);
            o[2] += p * lo16(v0.y); o[3] += p * hi16(v0.y);
            o[4] += p * lo16(v0.z); o[5] += p * hi16(v0.z);
            o[6] += p * lo16(v0.w); o[7] += p * hi16(v0.w);
            o[8] += p * lo16(v1.x); o[9] += p * hi16(v1.x);
            o[10] += p * lo16(v1.y); o[11] += p * hi16(v1.y);
            o[12] += p * lo16(v1.z); o[13] += p * hi16(v1.z);
            o[14] += p * lo16(v1.w); o[15] += p * hi16(v1.w);
        }
        m = mn;
    }
    float inv = 1.f / l;
    unsigned short* op = attnb + (size_t)token * 128 + head * 32 + dh * 16;
    uint4 ov;
    ov.x = bfp2(o[0] * inv, o[1] * inv); ov.y = bfp2(o[2] * inv, o[3] * inv);
    ov.z = bfp2(o[4] * inv, o[5] * inv); ov.w = bfp2(o[6] * inv, o[7] * inv);
    *(uint4*)op = ov;
    ov.x = bfp2(o[8] * inv, o[9] * inv); ov.y = bfp2(o[10] * inv, o[11] * inv);
    ov.z = bfp2(o[12] * inv, o[13] * inv); ov.w = bfp2(o[14] * inv, o[15] * inv);
    *(uint4*)(op + 8) = ov;
}

// ---------------- kpm2: proj+LN2+fc1+GELU+fc2+residuals, WAVE-AUTONOMOUS ----------
// 256 blocks x 256 threads (4 independent waves, 16 tokens each). ZERO barriers.
// All GEMMs operand-swapped: D[col][token], token = l16 -> LN lane-local (+2 shfl),
// h resident in REGISTERS (proj D and fc2 D share the same lane mapping).
// hn/y1 bounce through wave-private LDS slices (4KB each); fc1/fc2 chunk hid by 128.
// Weights read as fragments directly from global (L2-resident).
__global__ __launch_bounds__(256) void kpm2(bfp16 attnb, fp x, bfp16 wt1, fp pb,
                                            fp g2, fp b2, bfp16 wt2, fp b1v,
                                            bfp16 wt3, fp b2v, float* __restrict__ out) {
    __shared__ unsigned int lds[8192];   // [wid*1024): hn | [4096+wid*1024): y1 chunk
    const int tid = threadIdx.x;
    const int lane = tid & 63, wid = tid >> 6, quad = lane >> 4, l16 = lane & 15;
    const int tok = blockIdx.x * 64 + wid * 16 + l16;   // this lane's token
    const int HN = wid * 1024;
    const int Y1 = 4096 + wid * 1024;

    // ---- proj: D[col][tok]; A = wt1 rows (out-cols), B = attnb token frags ----
    bf16x8 bfr[4];
#pragma unroll
    for (int kk = 0; kk < 4; kk++)
        bfr[kk] = *(const bf16x8*)(attnb + (size_t)tok * CDIM + kk * 32 + quad * 8);

    float h[8][4];
    float sum = 0.f, sq = 0.f;
#pragma unroll
    for (int nt = 0; nt < 8; nt++) {
        f32x4 acc = (f32x4){0.f, 0.f, 0.f, 0.f};
#pragma unroll
        for (int kk = 0; kk < 4; kk++) {
            bf16x8 af = *(const bf16x8*)(wt1 + (size_t)(nt * 16 + l16) * 128 + kk * 32 + quad * 8);
            acc = __builtin_amdgcn_mfma_f32_16x16x32_bf16(af, bfr[kk], acc, 0, 0, 0);
        }
        const float4 pbv = *(const float4*)(pb + nt * 16 + quad * 4);
        const float4 xv  = *(const float4*)(x + (size_t)tok * CDIM + nt * 16 + quad * 4);
        h[nt][0] = xv.x + acc[0] + pbv.x;
        h[nt][1] = xv.y + acc[1] + pbv.y;
        h[nt][2] = xv.z + acc[2] + pbv.z;
        h[nt][3] = xv.w + acc[3] + pbv.w;
#pragma unroll
        for (int r = 0; r < 4; r++) { sum += h[nt][r]; sq += h[nt][r] * h[nt][r]; }
    }
    sum += __shfl_xor(sum, 16); sum += __shfl_xor(sum, 32);
    sq  += __shfl_xor(sq, 16);  sq  += __shfl_xor(sq, 32);
    float mu = sum * (1.f / 128.f);
    float rs = rsqrtf(sq * (1.f / 128.f) - mu * mu + LEPS);

    // hn -> wave-private LDS slice ([16 tok][128] bf16, 16B-chunk ^ l16 swizzle)
#pragma unroll
    for (int nt = 0; nt < 8; nt++) {
        const float4 gv = *(const float4*)(g2 + nt * 16 + quad * 4);
        const float4 bv = *(const float4*)(b2 + nt * 16 + quad * 4);
        uint2 val;
        val.x = bfp2((h[nt][0] - mu) * rs * gv.x + bv.x, (h[nt][1] - mu) * rs * gv.y + bv.y);
        val.y = bfp2((h[nt][2] - mu) * rs * gv.z + bv.z, (h[nt][3] - mu) * rs * gv.w + bv.w);
        int c16 = nt * 2 + (quad >> 1);
        *(uint2*)&lds[HN + l16 * 64 + ((c16 ^ l16) << 2) + ((quad & 1) << 1)] = val;
    }

    // ---- fc1 + GELU + fc2, hid chunked by 128; all wave-local ----
    f32x4 facc[8];
#pragma unroll
    for (int nt = 0; nt < 8; nt++) facc[nt] = (f32x4){0.f, 0.f, 0.f, 0.f};

    for (int hc = 0; hc < 4; hc++) {
#pragma unroll
        for (int ht = 0; ht < 8; ht++) {
            f32x4 a1 = (f32x4){0.f, 0.f, 0.f, 0.f};
#pragma unroll
            for (int kk = 0; kk < 4; kk++) {
                bf16x8 wf = *(const bf16x8*)(wt2 + (size_t)(hc * 128 + ht * 16 + l16) * 128 + kk * 32 + quad * 8);
                bf16x8 hb = *(bf16x8*)&lds[HN + l16 * 64 + (((kk * 4 + quad) ^ l16) << 2)];
                a1 = __builtin_amdgcn_mfma_f32_16x16x32_bf16(wf, hb, a1, 0, 0, 0);
            }
            const float4 b1q = *(const float4*)(b1v + hc * 128 + ht * 16 + quad * 4);
            float z0 = a1[0] + b1q.x, z1 = a1[1] + b1q.y, z2 = a1[2] + b1q.z, z3 = a1[3] + b1q.w;
            float g0 = 0.5f * z0 * (1.f + erff(z0 * 0.70710678118654752f));
            float g1 = 0.5f * z1 * (1.f + erff(z1 * 0.70710678118654752f));
            float g2v = 0.5f * z2 * (1.f + erff(z2 * 0.70710678118654752f));
            float g3 = 0.5f * z3 * (1.f + erff(z3 * 0.70710678118654752f));
            uint2 val; val.x = bfp2(g0, g1); val.y = bfp2(g2v, g3);
            int c16y = ht * 2 + (quad >> 1);
            *(uint2*)&lds[Y1 + l16 * 64 + ((c16y ^ l16) << 2) + ((quad & 1) << 1)] = val;
        }
#pragma unroll
        for (int nt = 0; nt < 8; nt++) {
#pragma unroll
            for (int kk = 0; kk < 4; kk++) {
                bf16x8 wf = *(const bf16x8*)(wt3 + (size_t)(nt * 16 + l16) * 512 + hc * 128 + kk * 32 + quad * 8);
                bf16x8 yb = *(bf16x8*)&lds[Y1 + l16 * 64 + (((kk * 4 + quad) ^ l16) << 2)];
                facc[nt] = __builtin_amdgcn_mfma_f32_16x16x32_bf16(wf, yb, facc[nt], 0, 0, 0);
            }
        }
    }

    // ---- out = h + fc2 + b2 (register residual; 16B stores) ----
#pragma unroll
    for (int nt = 0; nt < 8; nt++) {
        const float4 b2q = *(const float4*)(b2v + nt * 16 + quad * 4);
        float4 o;
        o.x = h[nt][0] + facc[nt][0] + b2q.x;
        o.y = h[nt][1] + facc[nt][1] + b2q.y;
        o.z = h[nt][2] + facc[nt][2] + b2q.z;
        o.w = h[nt][3] + facc[nt][3] + b2q.w;
        *(float4*)(out + (size_t)tok * CDIM + nt * 16 + quad * 4) = o;
    }
}

extern "C" void kernel_launch(void* const* d_in, const int* in_sizes, int n_in,
                              void* d_out, int out_size, void* d_ws, size_t ws_size,
                              hipStream_t stream) {
    fp x      = (fp)d_in[0];
    fp ln1_g  = (fp)d_in[1];
    fp ln1_b  = (fp)d_in[2];
    fp qkv_w  = (fp)d_in[3];
    fp qkv_b  = (fp)d_in[4];
    fp rpb    = (fp)d_in[5];
    fp proj_w = (fp)d_in[6];
    fp proj_b = (fp)d_in[7];
    fp ln2_g  = (fp)d_in[8];
    fp ln2_b  = (fp)d_in[9];
    fp fc1_w  = (fp)d_in[10];
    fp fc1_b  = (fp)d_in[11];
    fp fc2_w  = (fp)d_in[12];
    fp fc2_b  = (fp)d_in[13];
    float* out = (float*)d_out;

    float* ws = (float*)d_ws;
    float* h  = ws;                                                    // (spare)
    unsigned short* xn = (unsigned short*)(h + (size_t)TOKS * CDIM);   // (spare)
    unsigned short* hn = xn + (size_t)TOKS * CDIM;                     // (spare)
    float* qb = (float*)(hn + (size_t)TOKS * CDIM);
    unsigned short* kvb   = (unsigned short*)(qb + (size_t)TOKS * CDIM);
    unsigned short* attnb = kvb + (size_t)TOKS * 256;
    unsigned short* wt    = attnb + (size_t)TOKS * CDIM;

    unsigned short* wt0 = wt;            // qkv  [384][128]
    unsigned short* wt1 = wt + 49152;    // proj [128][128]
    unsigned short* wt2 = wt + 65536;    // fc1  [512][128]
    unsigned short* wt3 = wt + 131072;   // fc2  [128][512]

    prep<<<768, 256, 0, stream>>>(qkv_w, proj_w, fc1_w, fc2_w, wt);
    k1_mfma<<<dim3(TOKS / 128, 6), 256, 0, stream>>>(x, ln1_g, ln1_b, wt0, qkv_b, qb, kvb);
    k2_attn<<<TOKS / 64, 512, 0, stream>>>(qb, kvb, rpb, attnb);
    kpm2<<<TOKS / 64, 256, 0, stream>>>(attnb, x, wt1, proj_b, ln2_g, ln2_b,
                                        wt2, fc1_b, wt3, fc2_b, out);
}

// Round 11
// 131.958 us; speedup vs baseline: 1.3467x; 1.3467x over previous
//
#include <hip/hip_runtime.h>
#include <math.h>

#define TOKS 16384
#define CDIM 128
#define NH 4
#define HD 32
#define HID 512
#define QSCALE 0.17677669529663687f
#define LEPS 1e-5f

typedef const float* fp;
typedef const unsigned short* bfp16;
typedef __attribute__((ext_vector_type(8))) short bf16x8;
typedef __attribute__((ext_vector_type(4))) float f32x4;

__device__ inline unsigned int bfp2(float a, float b) {
    unsigned int ua = __float_as_uint(a); ua = (ua + 0x7FFFu + ((ua >> 16) & 1u)) >> 16;
    unsigned int ub = __float_as_uint(b); ub = (ub + 0x7FFFu + ((ub >> 16) & 1u)) >> 16;
    return ua | (ub << 16);
}
__device__ inline unsigned short bf1(float a) {
    unsigned int u = __float_as_uint(a);
    return (unsigned short)((u + 0x7FFFu + ((u >> 16) & 1u)) >> 16);
}
__device__ inline float lo16(unsigned int u) { return __uint_as_float(u << 16); }
__device__ inline float hi16(unsigned int u) { return __uint_as_float(u & 0xFFFF0000u); }

// ---------------- prep: weight convert+transpose (768 blocks) ----------------
// wt0: [n][k] rows (k1 stages to LDS).  wt1/wt2/wt3: FRAGMENT-MAJOR — each 16x32
// MFMA fragment stored as contiguous 1KB: elem((frag*64 + lane)*8 + e) =
// W[rt*16 + (lane&15)][kk*32 + (lane>>4)*8 + e].
__global__ __launch_bounds__(256) void prep(fp qw, fp pw, fp f1w, fp f2w,
                                            unsigned short* __restrict__ wt) {
    int e = blockIdx.x * 256 + threadIdx.x;
    float v;
    if (e < 49152) { int n = e >> 7, k = e & 127; v = qw[(size_t)k * 384 + n]; }
    else if (e < 65536) {        // wt1f: proj W[128 out][128 k], 32 frags (rt*4+kk)
        int i = e - 49152;
        int frag = i >> 9, w = i & 511, lane = w >> 3, el = w & 7;
        int rt = frag >> 2, kk = frag & 3;
        int row = rt * 16 + (lane & 15);
        int k = kk * 32 + (lane >> 4) * 8 + el;
        v = pw[(size_t)k * 128 + row];
    } else if (e < 131072) {     // wt2f: fc1 W[512 hid][128 k], 128 frags (rt*4+kk)
        int i = e - 65536;
        int frag = i >> 9, w = i & 511, lane = w >> 3, el = w & 7;
        int rt = frag >> 2, kk = frag & 3;
        int row = rt * 16 + (lane & 15);
        int k = kk * 32 + (lane >> 4) * 8 + el;
        v = f1w[(size_t)k * 512 + row];
    } else {                     // wt3f: fc2 W[128 out][512 k], 128 frags (rt*16+kc)
        int i = e - 131072;
        int frag = i >> 9, w = i & 511, lane = w >> 3, el = w & 7;
        int rt = frag >> 4, kc = frag & 15;
        int row = rt * 16 + (lane & 15);
        int k = kc * 32 + (lane >> 4) * 8 + el;
        v = f2w[(size_t)k * 128 + row];
    }
    wt[e] = bf1(v);
}

// ---------------- k1: fused LN1(x) + QKV GEMM (K=128, N=384); Q->f32, K/V->bf16 ------
__global__ __launch_bounds__(256) void k1_mfma(fp x, fp g1, fp b1, bfp16 wt0, fp wb,
                                               float* __restrict__ qb,
                                               unsigned short* __restrict__ kvb) {
    __shared__ unsigned int lds[12288];
    const int m0 = blockIdx.x * 128;
    const int nb = blockIdx.y * 64;
    const int tid = threadIdx.x;
#pragma unroll
    for (int i = 0; i < 8; i++) {
        int slot = tid + i * 256;
        int m = slot >> 4, c16 = slot & 15;
        const float4 v0 = *(const float4*)(x + (size_t)(m0 + m) * CDIM + c16 * 8);
        const float4 v1 = *(const float4*)(x + (size_t)(m0 + m) * CDIM + c16 * 8 + 4);
        float s = v0.x + v0.y + v0.z + v0.w + v1.x + v1.y + v1.z + v1.w;
        float q = v0.x * v0.x + v0.y * v0.y + v0.z * v0.z + v0.w * v0.w
                + v1.x * v1.x + v1.y * v1.y + v1.z * v1.z + v1.w * v1.w;
#pragma unroll
        for (int mm = 8; mm >= 1; mm >>= 1) { s += __shfl_xor(s, mm); q += __shfl_xor(q, mm); }
        float mu = s * (1.f / 128.f);
        float rs = rsqrtf(q * (1.f / 128.f) - mu * mu + LEPS);
        const float4 ga = *(const float4*)(g1 + c16 * 8);
        const float4 gb = *(const float4*)(g1 + c16 * 8 + 4);
        const float4 ba = *(const float4*)(b1 + c16 * 8);
        const float4 bb = *(const float4*)(b1 + c16 * 8 + 4);
        uint4 o;
        o.x = bfp2((v0.x - mu) * rs * ga.x + ba.x, (v0.y - mu) * rs * ga.y + ba.y);
        o.y = bfp2((v0.z - mu) * rs * ga.z + ba.z, (v0.w - mu) * rs * ga.w + ba.w);
        o.z = bfp2((v1.x - mu) * rs * gb.x + bb.x, (v1.y - mu) * rs * gb.y + bb.y);
        o.w = bfp2((v1.z - mu) * rs * gb.z + bb.z, (v1.w - mu) * rs * gb.w + bb.w);
        *(uint4*)&lds[m * 64 + ((c16 ^ (m & 15)) << 2)] = o;
    }
#pragma unroll
    for (int i = 0; i < 4; i++) {
        int slot = tid + i * 256;
        int n = slot >> 4, c16 = slot & 15;
        const uint4 v4 = *(const uint4*)(wt0 + (size_t)(nb + n) * 128 + c16 * 8);
        *(uint4*)&lds[8192 + n * 64 + (c16 ^ (n & 15)) * 4] = v4;
    }
    __syncthreads();

    const int lane = tid & 63, wid = tid >> 6, quad = lane >> 4, l16 = lane & 15;
    f32x4 acc[2][4];
#pragma unroll
    for (int mt = 0; mt < 2; mt++)
#pragma unroll
        for (int nt = 0; nt < 4; nt++) acc[mt][nt] = (f32x4){0.f, 0.f, 0.f, 0.f};
#pragma unroll
    for (int kk = 0; kk < 4; kk++) {
        int c = kk * 4 + quad;
        bf16x8 a0 = *(bf16x8*)&lds[(wid * 32 + l16) * 64 + (c ^ l16) * 4];
        bf16x8 a1 = *(bf16x8*)&lds[(wid * 32 + 16 + l16) * 64 + (c ^ l16) * 4];
#pragma unroll
        for (int nt = 0; nt < 4; nt++) {
            bf16x8 bf = *(bf16x8*)&lds[8192 + (nt * 16 + l16) * 64 + (c ^ l16) * 4];
            acc[0][nt] = __builtin_amdgcn_mfma_f32_16x16x32_bf16(a0, bf, acc[0][nt], 0, 0, 0);
            acc[1][nt] = __builtin_amdgcn_mfma_f32_16x16x32_bf16(a1, bf, acc[1][nt], 0, 0, 0);
        }
    }
#pragma unroll
    for (int nt = 0; nt < 4; nt++) {
        int col = nb + nt * 16 + l16;
        float bias = wb[col];
#pragma unroll
        for (int mt = 0; mt < 2; mt++)
#pragma unroll
            for (int r = 0; r < 4; r++) {
                int row = m0 + wid * 32 + mt * 16 + quad * 4 + r;
                float vres = acc[mt][nt][r] + bias;
                if (col < 128)
                    qb[(size_t)row * 128 + col] = vres * QSCALE;
                else if (col < 256)
                    kvb[(size_t)row * 256 + (col - 128)] = bf1(vres);
                else
                    kvb[(size_t)row * 256 + 128 + (col - 256)] = bf1(vres);
            }
    }
}

// ---------------- k2: tiled neighborhood attention (R6-verified version) ----------
__global__ __launch_bounds__(512) void k2_attn(const float* __restrict__ qb,
                                               const unsigned short* __restrict__ kvb,
                                               fp rpb, unsigned short* __restrict__ attnb) {
    __shared__ unsigned int lds[25088];          // 196 rows x 128 uints (K 64 | V 64)
    const int tile = blockIdx.x;                 // 256 tiles
    const int bb = tile >> 6;
    const int ty0 = ((tile >> 3) & 7) << 3;
    const int tx0 = (tile & 7) << 3;
    const int ry0 = min(max(ty0 - 3, 0), 50);
    const int rx0 = min(max(tx0 - 3, 0), 50);
    const int tid = threadIdx.x;

#pragma unroll
    for (int it = 0; it < 13; it++) {
        int slot = it * 512 + tid;
        if (slot < 6272) {
            int r = slot >> 5, c = slot & 31;
            int i = r / 14, j = r - i * 14;
            const uint4 v = *(const uint4*)(kvb + (size_t)((bb << 12) + (ry0 + i) * 64 + rx0 + j) * 256 + c * 8);
            *(uint4*)&lds[r * 128 + ((c ^ (r & 7)) << 2)] = v;
        }
    }

    const int dh = tid & 1;
    const int head = (tid >> 1) & 3;
    const int t = tid >> 3;
    const int tx = t & 7, ty = t >> 3;
    const int y = ty0 + ty, x = tx0 + tx;
    const int token = (bb << 12) + y * 64 + x;
    const int sy = min(max(y - 3, 0), 57);
    const int sx = min(max(x - 3, 0), 57);
    const int ib = sy - ry0, jb = sx - rx0;
    const float* rp = rpb + head * 169 + (sy - y + 6) * 13 + (sx - x + 6);

    float q[16];
    {
        const float4* qp = (const float4*)(qb + (size_t)token * 128 + head * 32 + dh * 16);
        float4 a = qp[0], b = qp[1], c = qp[2], d = qp[3];
        q[0] = a.x; q[1] = a.y; q[2] = a.z; q[3] = a.w;
        q[4] = b.x; q[5] = b.y; q[6] = b.z; q[7] = b.w;
        q[8] = c.x; q[9] = c.y; q[10] = c.z; q[11] = c.w;
        q[12] = d.x; q[13] = d.y; q[14] = d.z; q[15] = d.w;
    }
    __syncthreads();

    const int cb = (head << 2) + (dh << 1);
    float m = -1e30f, l = 0.f;
    float o[16];
#pragma unroll
    for (int i2 = 0; i2 < 16; i2++) o[i2] = 0.f;

    for (int dy = 0; dy < 7; dy++) {
        float s[7];
#pragma unroll
        for (int dx = 0; dx < 7; dx++) {
            int r = (ib + dy) * 14 + jb + dx;
            int sw = r & 7;
            const uint4 k0 = *(const uint4*)&lds[r * 128 + ((cb ^ sw) << 2)];
            const uint4 k1 = *(const uint4*)&lds[r * 128 + (((cb + 1) ^ sw) << 2)];
            float ss = q[0] * lo16(k0.x) + q[1] * hi16(k0.x)
                     + q[2] * lo16(k0.y) + q[3] * hi16(k0.y)
                     + q[4] * lo16(k0.z) + q[5] * hi16(k0.z)
                     + q[6] * lo16(k0.w) + q[7] * hi16(k0.w)
                     + q[8] * lo16(k1.x) + q[9] * hi16(k1.x)
                     + q[10] * lo16(k1.y) + q[11] * hi16(k1.y)
                     + q[12] * lo16(k1.z) + q[13] * hi16(k1.z)
                     + q[14] * lo16(k1.w) + q[15] * hi16(k1.w);
            ss += __shfl_xor(ss, 1);
            s[dx] = ss + rp[dy * 13 + dx];
        }
        float rm = s[0];
#pragma unroll
        for (int dx = 1; dx < 7; dx++) rm = fmaxf(rm, s[dx]);
        float mn = fmaxf(m, rm);
        float cf = __expf(m - mn);
        l *= cf;
#pragma unroll
        for (int i2 = 0; i2 < 16; i2++) o[i2] *= cf;
#pragma unroll
        for (int dx = 0; dx < 7; dx++) {
            int r = (ib + dy) * 14 + jb + dx;
            int sw = r & 7;
            const uint4 v0 = *(const uint4*)&lds[r * 128 + (((cb + 16) ^ sw) << 2)];
            const uint4 v1 = *(const uint4*)&lds[r * 128 + (((cb + 17) ^ sw) << 2)];
            float p = __expf(s[dx] - mn);
            l += p;
            o[0] += p * lo16(v0.x); o[1] += p * hi16(v0.x);
            o[2] += p * lo16(v0.y); o[3] += p * hi16(v0.y);
            o[4] += p * lo16(v0.z); o[5] += p * hi16(v0.z);
            o[6] += p * lo16(v0.w); o[7] += p * hi16(v0.w);
            o[8] += p * lo16(v1.x); o[9] += p * hi16(v1.x);
            o[10] += p * lo16(v1.y); o[11] += p * hi16(v1.y);
            o[12] += p * lo16(v1.z); o[13] += p * hi16(v1.z);
            o[14] += p * lo16(v1.w); o[15] += p * hi16(v1.w);
        }
        m = mn;
    }
    float inv = 1.f / l;
    unsigned short* op = attnb + (size_t)token * 128 + head * 32 + dh * 16;
    uint4 ov;
    ov.x = bfp2(o[0] * inv, o[1] * inv); ov.y = bfp2(o[2] * inv, o[3] * inv);
    ov.z = bfp2(o[4] * inv, o[5] * inv); ov.w = bfp2(o[6] * inv, o[7] * inv);
    *(uint4*)op = ov;
    ov.x = bfp2(o[8] * inv, o[9] * inv); ov.y = bfp2(o[10] * inv, o[11] * inv);
    ov.z = bfp2(o[12] * inv, o[13] * inv); ov.w = bfp2(o[14] * inv, o[15] * inv);
    *(uint4*)(op + 8) = ov;
}

// ---------------- kpm3: proj+LN2+fc1+GELU+fc2+residuals; frag-major weights ----------
// 512 blocks x 256 threads (4 waves), 32 tokens/block, LDS 48KB -> 3 blocks/CU.
// LDS: A_attn [0,2048) | hn [2048,4096) | y1 [4096,12288) (uints). h in REGISTERS:
// proj and fc2 share the same (mt,nhf) wave-tiling so residual is a register add
// (identical FP order to kpm). Weight operands are contiguous 1KB frag-major loads.
__global__ __launch_bounds__(256) void kpm3(bfp16 attnb, fp x, bfp16 wt1, fp pb,
                                            fp g2, fp b2, bfp16 wt2, fp b1v,
                                            bfp16 wt3, fp b2v, float* __restrict__ out) {
    __shared__ unsigned int lds[12288];
    float* ldsf = (float*)lds;
    unsigned short* ldsu = (unsigned short*)lds;
    const int m0 = blockIdx.x * 32;
    const int tid = threadIdx.x;
    const int lane = tid & 63, wid = tid >> 6, quad = lane >> 4, l16 = lane & 15;

    // stage attn tile
#pragma unroll
    for (int i = 0; i < 2; i++) {
        int slot = tid + i * 256;
        int m = slot >> 4, c16 = slot & 15;
        const uint4 v4 = *(const uint4*)(attnb + (size_t)(m0 + m) * CDIM + c16 * 8);
        *(uint4*)&lds[m * 64 + ((c16 ^ (m & 15)) << 2)] = v4;
    }
    __syncthreads();

    // ---- proj: wave (mt = wid&1 token-tile, nhf = wid>>1 col-half) ----
    const int mt = wid & 1, nhf = wid >> 1;
    f32x4 pacc[4];
#pragma unroll
    for (int nt = 0; nt < 4; nt++) pacc[nt] = (f32x4){0.f, 0.f, 0.f, 0.f};
#pragma unroll
    for (int kk = 0; kk < 4; kk++) {
        int c = kk * 4 + quad;
        bf16x8 a = *(bf16x8*)&lds[(mt * 16 + l16) * 64 + ((c ^ l16) << 2)];
#pragma unroll
        for (int nt = 0; nt < 4; nt++) {
            bf16x8 bf = *(const bf16x8*)(wt1 + (size_t)((((nhf * 4 + nt) * 4 + kk) * 64 + lane)) * 8);
            pacc[nt] = __builtin_amdgcn_mfma_f32_16x16x32_bf16(a, bf, pacc[nt], 0, 0, 0);
        }
    }
    // h = x + proj + pb (REGISTERS); per-row stats over this wave's 64 cols
    float sr[4] = {0.f, 0.f, 0.f, 0.f}, qr[4] = {0.f, 0.f, 0.f, 0.f};
#pragma unroll
    for (int nt = 0; nt < 4; nt++) {
        int col = nhf * 64 + nt * 16 + l16;
        float bias = pb[col];
#pragma unroll
        for (int r = 0; r < 4; r++) {
            int lrow = mt * 16 + quad * 4 + r;
            float hv = x[(size_t)(m0 + lrow) * CDIM + col] + pacc[nt][r] + bias;
            pacc[nt][r] = hv;
            sr[r] += hv; qr[r] += hv * hv;
        }
    }
#pragma unroll
    for (int mm = 1; mm <= 8; mm <<= 1) {
#pragma unroll
        for (int r = 0; r < 4; r++) {
            sr[r] += __shfl_xor(sr[r], mm);
            qr[r] += __shfl_xor(qr[r], mm);
        }
    }
    __syncthreads();   // A region dead -> stats scratch
    if (l16 == 0) {
#pragma unroll
        for (int r = 0; r < 4; r++) {
            ldsf[wid * 32 + (quad * 4 + r) * 2]     = sr[r];
            ldsf[wid * 32 + (quad * 4 + r) * 2 + 1] = qr[r];
        }
    }
    __syncthreads();
    float mu[4], rs[4];
#pragma unroll
    for (int r = 0; r < 4; r++) {
        int po = (wid ^ 2) * 32 + (quad * 4 + r) * 2;   // partner: same mt, other nhf
        float st = sr[r] + ldsf[po];
        float qt = qr[r] + ldsf[po + 1];
        mu[r] = st * (1.f / 128.f);
        rs[r] = rsqrtf(qt * (1.f / 128.f) - mu[r] * mu[r] + LEPS);
    }
    // hn -> LDS (2B scatter into swizzled 16B chunks); base ldsu 4096 (uint 2048)
#pragma unroll
    for (int nt = 0; nt < 4; nt++) {
        int col = nhf * 64 + nt * 16 + l16;
        float gg = g2[col], bbv = b2[col];
        int c16h = col >> 3, cw = col & 7;
#pragma unroll
        for (int r = 0; r < 4; r++) {
            int lrow = mt * 16 + quad * 4 + r;
            ldsu[4096 + lrow * 128 + ((c16h ^ (lrow & 15)) << 3) + cw] =
                bf1((pacc[nt][r] - mu[r]) * rs[r] * gg + bbv);
        }
    }
    __syncthreads();

    // ---- fc1 + GELU: wave wid owns hid [wid*128, +128); frag-major wt2 ----
#pragma unroll
    for (int ht = 0; ht < 8; ht++) {
        f32x4 acc0 = (f32x4){0.f, 0.f, 0.f, 0.f};
        f32x4 acc1 = (f32x4){0.f, 0.f, 0.f, 0.f};
#pragma unroll
        for (int kk = 0; kk < 4; kk++) {
            int c = kk * 4 + quad;
            bf16x8 wf = *(const bf16x8*)(wt2 + (size_t)((((wid * 8 + ht) * 4 + kk) * 64 + lane)) * 8);
            bf16x8 x0 = *(bf16x8*)&lds[2048 + l16 * 64 + ((c ^ l16) << 2)];
            bf16x8 x1 = *(bf16x8*)&lds[2048 + (16 + l16) * 64 + ((c ^ l16) << 2)];
            acc0 = __builtin_amdgcn_mfma_f32_16x16x32_bf16(wf, x0, acc0, 0, 0, 0);
            acc1 = __builtin_amdgcn_mfma_f32_16x16x32_bf16(wf, x1, acc1, 0, 0, 0);
        }
        const int hidb = wid * 128 + ht * 16 + quad * 4;
        const float4 bb = *(const float4*)(b1v + hidb);
        const int c16y = hidb >> 3;
        const int woff = (quad & 1) << 1;
#pragma unroll
        for (int t = 0; t < 2; t++) {
            f32x4 a = t ? acc1 : acc0;
            int row = t * 16 + l16;
            float z0 = a[0] + bb.x, z1 = a[1] + bb.y, z2 = a[2] + bb.z, z3 = a[3] + bb.w;
            float g0 = 0.5f * z0 * (1.f + erff(z0 * 0.70710678118654752f));
            float g1 = 0.5f * z1 * (1.f + erff(z1 * 0.70710678118654752f));
            float g2v = 0.5f * z2 * (1.f + erff(z2 * 0.70710678118654752f));
            float g3 = 0.5f * z3 * (1.f + erff(z3 * 0.70710678118654752f));
            uint2 val; val.x = bfp2(g0, g1); val.y = bfp2(g2v, g3);
            *(uint2*)&lds[4096 + row * 256 + ((c16y ^ (row & 15)) << 2) + woff] = val;
        }
    }
    __syncthreads();

    // ---- fc2 + residual: wave (mt,nhf) = 16 tokens x 64 cols; K=512, kc ascending ----
    f32x4 facc[4];
#pragma unroll
    for (int nt = 0; nt < 4; nt++) facc[nt] = (f32x4){0.f, 0.f, 0.f, 0.f};
#pragma unroll
    for (int kc = 0; kc < 16; kc++) {
        int c = kc * 4 + quad;
        bf16x8 a = *(bf16x8*)&lds[4096 + (mt * 16 + l16) * 256 + ((c ^ l16) << 2)];
#pragma unroll
        for (int nt = 0; nt < 4; nt++) {
            bf16x8 bf = *(const bf16x8*)(wt3 + (size_t)((((nhf * 4 + nt) * 16 + kc) * 64 + lane)) * 8);
            facc[nt] = __builtin_amdgcn_mfma_f32_16x16x32_bf16(a, bf, facc[nt], 0, 0, 0);
        }
    }
#pragma unroll
    for (int nt = 0; nt < 4; nt++) {
        int col = nhf * 64 + nt * 16 + l16;
        float bias = b2v[col];
#pragma unroll
        for (int r = 0; r < 4; r++) {
            int lrow = mt * 16 + quad * 4 + r;
            out[(size_t)(m0 + lrow) * CDIM + col] = pacc[nt][r] + facc[nt][r] + bias;
        }
    }
}

extern "C" void kernel_launch(void* const* d_in, const int* in_sizes, int n_in,
                              void* d_out, int out_size, void* d_ws, size_t ws_size,
                              hipStream_t stream) {
    fp x      = (fp)d_in[0];
    fp ln1_g  = (fp)d_in[1];
    fp ln1_b  = (fp)d_in[2];
    fp qkv_w  = (fp)d_in[3];
    fp qkv_b  = (fp)d_in[4];
    fp rpb    = (fp)d_in[5];
    fp proj_w = (fp)d_in[6];
    fp proj_b = (fp)d_in[7];
    fp ln2_g  = (fp)d_in[8];
    fp ln2_b  = (fp)d_in[9];
    fp fc1_w  = (fp)d_in[10];
    fp fc1_b  = (fp)d_in[11];
    fp fc2_w  = (fp)d_in[12];
    fp fc2_b  = (fp)d_in[13];
    float* out = (float*)d_out;

    float* ws = (float*)d_ws;
    float* h  = ws;                                                    // (spare)
    unsigned short* xn = (unsigned short*)(h + (size_t)TOKS * CDIM);   // (spare)
    unsigned short* hn = xn + (size_t)TOKS * CDIM;                     // (spare)
    float* qb = (float*)(hn + (size_t)TOKS * CDIM);
    unsigned short* kvb   = (unsigned short*)(qb + (size_t)TOKS * CDIM);
    unsigned short* attnb = kvb + (size_t)TOKS * 256;
    unsigned short* wt    = attnb + (size_t)TOKS * CDIM;

    unsigned short* wt0 = wt;            // qkv  [384][128]
    unsigned short* wt1 = wt + 49152;    // proj frag-major
    unsigned short* wt2 = wt + 65536;    // fc1  frag-major
    unsigned short* wt3 = wt + 131072;   // fc2  frag-major

    prep<<<768, 256, 0, stream>>>(qkv_w, proj_w, fc1_w, fc2_w, wt);
    k1_mfma<<<dim3(TOKS / 128, 6), 256, 0, stream>>>(x, ln1_g, ln1_b, wt0, qkv_b, qb, kvb);
    k2_attn<<<TOKS / 64, 512, 0, stream>>>(qb, kvb, rpb, attnb);
    kpm3<<<TOKS / 32, 256, 0, stream>>>(attnb, x, wt1, proj_b, ln2_g, ln2_b,
                                        wt2, fc1_b, wt3, fc2_b, out);
}

// Round 12
// 130.846 us; speedup vs baseline: 1.3581x; 1.0085x over previous
//
#include <hip/hip_runtime.h>
#include <math.h>

#define TOKS 16384
#define CDIM 128
#define NH 4
#define HD 32
#define HID 512
#define QSCALE 0.17677669529663687f
#define LEPS 1e-5f

typedef const float* fp;
typedef const unsigned short* bfp16;
typedef __attribute__((ext_vector_type(8))) short bf16x8;
typedef __attribute__((ext_vector_type(4))) float f32x4;

__device__ inline unsigned int bfp2(float a, float b) {
    unsigned int ua = __float_as_uint(a); ua = (ua + 0x7FFFu + ((ua >> 16) & 1u)) >> 16;
    unsigned int ub = __float_as_uint(b); ub = (ub + 0x7FFFu + ((ub >> 16) & 1u)) >> 16;
    return ua | (ub << 16);
}
__device__ inline unsigned short bf1(float a) {
    unsigned int u = __float_as_uint(a);
    return (unsigned short)((u + 0x7FFFu + ((u >> 16) & 1u)) >> 16);
}
__device__ inline float lo16(unsigned int u) { return __uint_as_float(u << 16); }
__device__ inline float hi16(unsigned int u) { return __uint_as_float(u & 0xFFFF0000u); }

// ---------------- prep: weight convert+transpose (768 blocks) ----------------
// wt0: [n][k] rows (k1 stages to LDS).  wt1/wt2/wt3: FRAGMENT-MAJOR — each 16x32
// MFMA fragment stored as contiguous 1KB: elem((frag*64 + lane)*8 + e) =
// W[rt*16 + (lane&15)][kk*32 + (lane>>4)*8 + e].
__global__ __launch_bounds__(256) void prep(fp qw, fp pw, fp f1w, fp f2w,
                                            unsigned short* __restrict__ wt) {
    int e = blockIdx.x * 256 + threadIdx.x;
    float v;
    if (e < 49152) { int n = e >> 7, k = e & 127; v = qw[(size_t)k * 384 + n]; }
    else if (e < 65536) {        // wt1f: proj W[128 out][128 k], 32 frags (rt*4+kk)
        int i = e - 49152;
        int frag = i >> 9, w = i & 511, lane = w >> 3, el = w & 7;
        int rt = frag >> 2, kk = frag & 3;
        int row = rt * 16 + (lane & 15);
        int k = kk * 32 + (lane >> 4) * 8 + el;
        v = pw[(size_t)k * 128 + row];
    } else if (e < 131072) {     // wt2f: fc1 W[512 hid][128 k], 128 frags (rt*4+kk)
        int i = e - 65536;
        int frag = i >> 9, w = i & 511, lane = w >> 3, el = w & 7;
        int rt = frag >> 2, kk = frag & 3;
        int row = rt * 16 + (lane & 15);
        int k = kk * 32 + (lane >> 4) * 8 + el;
        v = f1w[(size_t)k * 512 + row];
    } else {                     // wt3f: fc2 W[128 out][512 k], 128 frags (rt*16+kc)
        int i = e - 131072;
        int frag = i >> 9, w = i & 511, lane = w >> 3, el = w & 7;
        int rt = frag >> 4, kc = frag & 15;
        int row = rt * 16 + (lane & 15);
        int k = kc * 32 + (lane >> 4) * 8 + el;
        v = f2w[(size_t)k * 128 + row];
    }
    wt[e] = bf1(v);
}

// ---------------- k1: fused LN1(x) + QKV GEMM (K=128, N=384); Q->f32, K/V->bf16 ------
__global__ __launch_bounds__(256) void k1_mfma(fp x, fp g1, fp b1, bfp16 wt0, fp wb,
                                               float* __restrict__ qb,
                                               unsigned short* __restrict__ kvb) {
    __shared__ unsigned int lds[12288];
    const int m0 = blockIdx.x * 128;
    const int nb = blockIdx.y * 64;
    const int tid = threadIdx.x;
#pragma unroll
    for (int i = 0; i < 8; i++) {
        int slot = tid + i * 256;
        int m = slot >> 4, c16 = slot & 15;
        const float4 v0 = *(const float4*)(x + (size_t)(m0 + m) * CDIM + c16 * 8);
        const float4 v1 = *(const float4*)(x + (size_t)(m0 + m) * CDIM + c16 * 8 + 4);
        float s = v0.x + v0.y + v0.z + v0.w + v1.x + v1.y + v1.z + v1.w;
        float q = v0.x * v0.x + v0.y * v0.y + v0.z * v0.z + v0.w * v0.w
                + v1.x * v1.x + v1.y * v1.y + v1.z * v1.z + v1.w * v1.w;
#pragma unroll
        for (int mm = 8; mm >= 1; mm >>= 1) { s += __shfl_xor(s, mm); q += __shfl_xor(q, mm); }
        float mu = s * (1.f / 128.f);
        float rs = rsqrtf(q * (1.f / 128.f) - mu * mu + LEPS);
        const float4 ga = *(const float4*)(g1 + c16 * 8);
        const float4 gb = *(const float4*)(g1 + c16 * 8 + 4);
        const float4 ba = *(const float4*)(b1 + c16 * 8);
        const float4 bb = *(const float4*)(b1 + c16 * 8 + 4);
        uint4 o;
        o.x = bfp2((v0.x - mu) * rs * ga.x + ba.x, (v0.y - mu) * rs * ga.y + ba.y);
        o.y = bfp2((v0.z - mu) * rs * ga.z + ba.z, (v0.w - mu) * rs * ga.w + ba.w);
        o.z = bfp2((v1.x - mu) * rs * gb.x + bb.x, (v1.y - mu) * rs * gb.y + bb.y);
        o.w = bfp2((v1.z - mu) * rs * gb.z + bb.z, (v1.w - mu) * rs * gb.w + bb.w);
        *(uint4*)&lds[m * 64 + ((c16 ^ (m & 15)) << 2)] = o;
    }
#pragma unroll
    for (int i = 0; i < 4; i++) {
        int slot = tid + i * 256;
        int n = slot >> 4, c16 = slot & 15;
        const uint4 v4 = *(const uint4*)(wt0 + (size_t)(nb + n) * 128 + c16 * 8);
        *(uint4*)&lds[8192 + n * 64 + (c16 ^ (n & 15)) * 4] = v4;
    }
    __syncthreads();

    const int lane = tid & 63, wid = tid >> 6, quad = lane >> 4, l16 = lane & 15;
    f32x4 acc[2][4];
#pragma unroll
    for (int mt = 0; mt < 2; mt++)
#pragma unroll
        for (int nt = 0; nt < 4; nt++) acc[mt][nt] = (f32x4){0.f, 0.f, 0.f, 0.f};
#pragma unroll
    for (int kk = 0; kk < 4; kk++) {
        int c = kk * 4 + quad;
        bf16x8 a0 = *(bf16x8*)&lds[(wid * 32 + l16) * 64 + (c ^ l16) * 4];
        bf16x8 a1 = *(bf16x8*)&lds[(wid * 32 + 16 + l16) * 64 + (c ^ l16) * 4];
#pragma unroll
        for (int nt = 0; nt < 4; nt++) {
            bf16x8 bf = *(bf16x8*)&lds[8192 + (nt * 16 + l16) * 64 + (c ^ l16) * 4];
            acc[0][nt] = __builtin_amdgcn_mfma_f32_16x16x32_bf16(a0, bf, acc[0][nt], 0, 0, 0);
            acc[1][nt] = __builtin_amdgcn_mfma_f32_16x16x32_bf16(a1, bf, acc[1][nt], 0, 0, 0);
        }
    }
#pragma unroll
    for (int nt = 0; nt < 4; nt++) {
        int col = nb + nt * 16 + l16;
        float bias = wb[col];
#pragma unroll
        for (int mt = 0; mt < 2; mt++)
#pragma unroll
            for (int r = 0; r < 4; r++) {
                int row = m0 + wid * 32 + mt * 16 + quad * 4 + r;
                float vres = acc[mt][nt][r] + bias;
                if (col < 128)
                    qb[(size_t)row * 128 + col] = vres * QSCALE;
                else if (col < 256)
                    kvb[(size_t)row * 256 + (col - 128)] = bf1(vres);
                else
                    kvb[(size_t)row * 256 + 128 + (col - 256)] = bf1(vres);
            }
    }
}

// ---------------- k2: tiled neighborhood attention (R6-verified version) ----------
__global__ __launch_bounds__(512) void k2_attn(const float* __restrict__ qb,
                                               const unsigned short* __restrict__ kvb,
                                               fp rpb, unsigned short* __restrict__ attnb) {
    __shared__ unsigned int lds[25088];          // 196 rows x 128 uints (K 64 | V 64)
    const int tile = blockIdx.x;                 // 256 tiles
    const int bb = tile >> 6;
    const int ty0 = ((tile >> 3) & 7) << 3;
    const int tx0 = (tile & 7) << 3;
    const int ry0 = min(max(ty0 - 3, 0), 50);
    const int rx0 = min(max(tx0 - 3, 0), 50);
    const int tid = threadIdx.x;

#pragma unroll
    for (int it = 0; it < 13; it++) {
        int slot = it * 512 + tid;
        if (slot < 6272) {
            int r = slot >> 5, c = slot & 31;
            int i = r / 14, j = r - i * 14;
            const uint4 v = *(const uint4*)(kvb + (size_t)((bb << 12) + (ry0 + i) * 64 + rx0 + j) * 256 + c * 8);
            *(uint4*)&lds[r * 128 + ((c ^ (r & 7)) << 2)] = v;
        }
    }

    const int dh = tid & 1;
    const int head = (tid >> 1) & 3;
    const int t = tid >> 3;
    const int tx = t & 7, ty = t >> 3;
    const int y = ty0 + ty, x = tx0 + tx;
    const int token = (bb << 12) + y * 64 + x;
    const int sy = min(max(y - 3, 0), 57);
    const int sx = min(max(x - 3, 0), 57);
    const int ib = sy - ry0, jb = sx - rx0;
    const float* rp = rpb + head * 169 + (sy - y + 6) * 13 + (sx - x + 6);

    float q[16];
    {
        const float4* qp = (const float4*)(qb + (size_t)token * 128 + head * 32 + dh * 16);
        float4 a = qp[0], b = qp[1], c = qp[2], d = qp[3];
        q[0] = a.x; q[1] = a.y; q[2] = a.z; q[3] = a.w;
        q[4] = b.x; q[5] = b.y; q[6] = b.z; q[7] = b.w;
        q[8] = c.x; q[9] = c.y; q[10] = c.z; q[11] = c.w;
        q[12] = d.x; q[13] = d.y; q[14] = d.z; q[15] = d.w;
    }
    __syncthreads();

    const int cb = (head << 2) + (dh << 1);
    float m = -1e30f, l = 0.f;
    float o[16];
#pragma unroll
    for (int i2 = 0; i2 < 16; i2++) o[i2] = 0.f;

    for (int dy = 0; dy < 7; dy++) {
        float s[7];
#pragma unroll
        for (int dx = 0; dx < 7; dx++) {
            int r = (ib + dy) * 14 + jb + dx;
            int sw = r & 7;
            const uint4 k0 = *(const uint4*)&lds[r * 128 + ((cb ^ sw) << 2)];
            const uint4 k1 = *(const uint4*)&lds[r * 128 + (((cb + 1) ^ sw) << 2)];
            float ss = q[0] * lo16(k0.x) + q[1] * hi16(k0.x)
                     + q[2] * lo16(k0.y) + q[3] * hi16(k0.y)
                     + q[4] * lo16(k0.z) + q[5] * hi16(k0.z)
                     + q[6] * lo16(k0.w) + q[7] * hi16(k0.w)
                     + q[8] * lo16(k1.x) + q[9] * hi16(k1.x)
                     + q[10] * lo16(k1.y) + q[11] * hi16(k1.y)
                     + q[12] * lo16(k1.z) + q[13] * hi16(k1.z)
                     + q[14] * lo16(k1.w) + q[15] * hi16(k1.w);
            ss += __shfl_xor(ss, 1);
            s[dx] = ss + rp[dy * 13 + dx];
        }
        float rm = s[0];
#pragma unroll
        for (int dx = 1; dx < 7; dx++) rm = fmaxf(rm, s[dx]);
        float mn = fmaxf(m, rm);
        float cf = __expf(m - mn);
        l *= cf;
#pragma unroll
        for (int i2 = 0; i2 < 16; i2++) o[i2] *= cf;
#pragma unroll
        for (int dx = 0; dx < 7; dx++) {
            int r = (ib + dy) * 14 + jb + dx;
            int sw = r & 7;
            const uint4 v0 = *(const uint4*)&lds[r * 128 + (((cb + 16) ^ sw) << 2)];
            const uint4 v1 = *(const uint4*)&lds[r * 128 + (((cb + 17) ^ sw) << 2)];
            float p = __expf(s[dx] - mn);
            l += p;
            o[0] += p * lo16(v0.x); o[1] += p * hi16(v0.x);
            o[2] += p * lo16(v0.y); o[3] += p * hi16(v0.y);
            o[4] += p * lo16(v0.z); o[5] += p * hi16(v0.z);
            o[6] += p * lo16(v0.w); o[7] += p * hi16(v0.w);
            o[8] += p * lo16(v1.x); o[9] += p * hi16(v1.x);
            o[10] += p * lo16(v1.y); o[11] += p * hi16(v1.y);
            o[12] += p * lo16(v1.z); o[13] += p * hi16(v1.z);
            o[14] += p * lo16(v1.w); o[15] += p * hi16(v1.w);
        }
        m = mn;
    }
    float inv = 1.f / l;
    unsigned short* op = attnb + (size_t)token * 128 + head * 32 + dh * 16;
    uint4 ov;
    ov.x = bfp2(o[0] * inv, o[1] * inv); ov.y = bfp2(o[2] * inv, o[3] * inv);
    ov.z = bfp2(o[4] * inv, o[5] * inv); ov.w = bfp2(o[6] * inv, o[7] * inv);
    *(uint4*)op = ov;
    ov.x = bfp2(o[8] * inv, o[9] * inv); ov.y = bfp2(o[10] * inv, o[11] * inv);
    ov.z = bfp2(o[12] * inv, o[13] * inv); ov.w = bfp2(o[14] * inv, o[15] * inv);
    *(uint4*)(op + 8) = ov;
}

// ---------------- kpm4: proj+LN2+fc1+GELU+fc2+residuals; 8 waves / 32 tokens --------
// 512 blocks x 512 threads (8 waves), 32 tokens/block, LDS 48KB -> 2 blocks/CU
// (block-count-bound at 512 blocks) = 16 waves/CU (2x kpm3's TLP).
// Same LDS layouts/swizzles/frag indices/FP-order as kpm3; phases split 2x finer:
// proj/fc2: wave (mt=wid&1, nhf=wid>>1 in 0..3) = 16 tok x 32 cols (nt<2);
// fc1: wave owns 64 hid rows (ht<4). LN2 stats: 4-way cross-wave combine.
__global__ __launch_bounds__(512) void kpm4(bfp16 attnb, fp x, bfp16 wt1, fp pb,
                                            fp g2, fp b2, bfp16 wt2, fp b1v,
                                            bfp16 wt3, fp b2v, float* __restrict__ out) {
    __shared__ unsigned int lds[12288];
    float* ldsf = (float*)lds;
    unsigned short* ldsu = (unsigned short*)lds;
    const int m0 = blockIdx.x * 32;
    const int tid = threadIdx.x;
    const int lane = tid & 63, wid = tid >> 6, quad = lane >> 4, l16 = lane & 15;

    // stage attn tile (512 threads, 1 slot each)
    {
        int m = tid >> 4, c16 = tid & 15;
        const uint4 v4 = *(const uint4*)(attnb + (size_t)(m0 + m) * CDIM + c16 * 8);
        *(uint4*)&lds[m * 64 + ((c16 ^ (m & 15)) << 2)] = v4;
    }
    __syncthreads();

    // ---- proj: wave (mt, nhf); 16 tok x 32 cols ----
    const int mt = wid & 1, nhf = wid >> 1;
    f32x4 pacc[2];
#pragma unroll
    for (int nt = 0; nt < 2; nt++) pacc[nt] = (f32x4){0.f, 0.f, 0.f, 0.f};
#pragma unroll
    for (int kk = 0; kk < 4; kk++) {
        int c = kk * 4 + quad;
        bf16x8 a = *(bf16x8*)&lds[(mt * 16 + l16) * 64 + ((c ^ l16) << 2)];
#pragma unroll
        for (int nt = 0; nt < 2; nt++) {
            int rt = nhf * 2 + nt;
            bf16x8 bf = *(const bf16x8*)(wt1 + (size_t)((rt * 4 + kk) * 64 + lane) * 8);
            pacc[nt] = __builtin_amdgcn_mfma_f32_16x16x32_bf16(a, bf, pacc[nt], 0, 0, 0);
        }
    }
    // h = x + proj + pb (REGISTERS); per-row partial stats over this wave's 32 cols
    float sr[4] = {0.f, 0.f, 0.f, 0.f}, qr[4] = {0.f, 0.f, 0.f, 0.f};
#pragma unroll
    for (int nt = 0; nt < 2; nt++) {
        int col = nhf * 32 + nt * 16 + l16;
        float bias = pb[col];
#pragma unroll
        for (int r = 0; r < 4; r++) {
            int lrow = mt * 16 + quad * 4 + r;
            float hv = x[(size_t)(m0 + lrow) * CDIM + col] + pacc[nt][r] + bias;
            pacc[nt][r] = hv;
            sr[r] += hv; qr[r] += hv * hv;
        }
    }
#pragma unroll
    for (int mm = 1; mm <= 8; mm <<= 1) {
#pragma unroll
        for (int r = 0; r < 4; r++) {
            sr[r] += __shfl_xor(sr[r], mm);
            qr[r] += __shfl_xor(qr[r], mm);
        }
    }
    __syncthreads();   // A region dead -> stats scratch
    if (l16 == 0) {
#pragma unroll
        for (int r = 0; r < 4; r++) {
            ldsf[wid * 32 + (quad * 4 + r) * 2]     = sr[r];
            ldsf[wid * 32 + (quad * 4 + r) * 2 + 1] = qr[r];
        }
    }
    __syncthreads();
    float mu[4], rs[4];
#pragma unroll
    for (int r = 0; r < 4; r++) {
        float st = 0.f, qt = 0.f;
#pragma unroll
        for (int p = 0; p < 4; p++) {            // same mt, all 4 nhf quarters, ascending
            int w2 = p * 2 + mt;
            st += ldsf[w2 * 32 + (quad * 4 + r) * 2];
            qt += ldsf[w2 * 32 + (quad * 4 + r) * 2 + 1];
        }
        mu[r] = st * (1.f / 128.f);
        rs[r] = rsqrtf(qt * (1.f / 128.f) - mu[r] * mu[r] + LEPS);
    }
    // hn -> LDS (2B scatter into swizzled 16B chunks); base ldsu 4096 (uint 2048)
#pragma unroll
    for (int nt = 0; nt < 2; nt++) {
        int col = nhf * 32 + nt * 16 + l16;
        float gg = g2[col], bbv = b2[col];
        int c16h = col >> 3, cw = col & 7;
#pragma unroll
        for (int r = 0; r < 4; r++) {
            int lrow = mt * 16 + quad * 4 + r;
            ldsu[4096 + lrow * 128 + ((c16h ^ (lrow & 15)) << 3) + cw] =
                bf1((pacc[nt][r] - mu[r]) * rs[r] * gg + bbv);
        }
    }
    __syncthreads();

    // ---- fc1 + GELU: wave wid owns hid [wid*64, +64); frag-major wt2 ----
#pragma unroll
    for (int ht = 0; ht < 4; ht++) {
        f32x4 acc0 = (f32x4){0.f, 0.f, 0.f, 0.f};
        f32x4 acc1 = (f32x4){0.f, 0.f, 0.f, 0.f};
#pragma unroll
        for (int kk = 0; kk < 4; kk++) {
            int c = kk * 4 + quad;
            bf16x8 wf = *(const bf16x8*)(wt2 + (size_t)(((wid * 4 + ht) * 4 + kk) * 64 + lane) * 8);
            bf16x8 x0 = *(bf16x8*)&lds[2048 + l16 * 64 + ((c ^ l16) << 2)];
            bf16x8 x1 = *(bf16x8*)&lds[2048 + (16 + l16) * 64 + ((c ^ l16) << 2)];
            acc0 = __builtin_amdgcn_mfma_f32_16x16x32_bf16(wf, x0, acc0, 0, 0, 0);
            acc1 = __builtin_amdgcn_mfma_f32_16x16x32_bf16(wf, x1, acc1, 0, 0, 0);
        }
        const int hidb = wid * 64 + ht * 16 + quad * 4;
        const float4 bb = *(const float4*)(b1v + hidb);
        const int c16y = hidb >> 3;
        const int woff = (quad & 1) << 1;
#pragma unroll
        for (int t = 0; t < 2; t++) {
            f32x4 a = t ? acc1 : acc0;
            int row = t * 16 + l16;
            float z0 = a[0] + bb.x, z1 = a[1] + bb.y, z2 = a[2] + bb.z, z3 = a[3] + bb.w;
            float g0 = 0.5f * z0 * (1.f + erff(z0 * 0.70710678118654752f));
            float g1 = 0.5f * z1 * (1.f + erff(z1 * 0.70710678118654752f));
            float g2v = 0.5f * z2 * (1.f + erff(z2 * 0.70710678118654752f));
            float g3 = 0.5f * z3 * (1.f + erff(z3 * 0.70710678118654752f));
            uint2 val; val.x = bfp2(g0, g1); val.y = bfp2(g2v, g3);
            *(uint2*)&lds[4096 + row * 256 + ((c16y ^ (row & 15)) << 2) + woff] = val;
        }
    }
    __syncthreads();

    // ---- fc2 + residual: wave (mt,nhf) = 16 tok x 32 cols; K=512, kc ascending ----
    f32x4 facc[2];
#pragma unroll
    for (int nt = 0; nt < 2; nt++) facc[nt] = (f32x4){0.f, 0.f, 0.f, 0.f};
#pragma unroll
    for (int kc = 0; kc < 16; kc++) {
        int c = kc * 4 + quad;
        bf16x8 a = *(bf16x8*)&lds[4096 + (mt * 16 + l16) * 256 + ((c ^ l16) << 2)];
#pragma unroll
        for (int nt = 0; nt < 2; nt++) {
            int rt = nhf * 2 + nt;
            bf16x8 bf = *(const bf16x8*)(wt3 + (size_t)((rt * 16 + kc) * 64 + lane) * 8);
            facc[nt] = __builtin_amdgcn_mfma_f32_16x16x32_bf16(a, bf, facc[nt], 0, 0, 0);
        }
    }
#pragma unroll
    for (int nt = 0; nt < 2; nt++) {
        int col = nhf * 32 + nt * 16 + l16;
        float bias = b2v[col];
#pragma unroll
        for (int r = 0; r < 4; r++) {
            int lrow = mt * 16 + quad * 4 + r;
            out[(size_t)(m0 + lrow) * CDIM + col] = pacc[nt][r] + facc[nt][r] + bias;
        }
    }
}

extern "C" void kernel_launch(void* const* d_in, const int* in_sizes, int n_in,
                              void* d_out, int out_size, void* d_ws, size_t ws_size,
                              hipStream_t stream) {
    fp x      = (fp)d_in[0];
    fp ln1_g  = (fp)d_in[1];
    fp ln1_b  = (fp)d_in[2];
    fp qkv_w  = (fp)d_in[3];
    fp qkv_b  = (fp)d_in[4];
    fp rpb    = (fp)d_in[5];
    fp proj_w = (fp)d_in[6];
    fp proj_b = (fp)d_in[7];
    fp ln2_g  = (fp)d_in[8];
    fp ln2_b  = (fp)d_in[9];
    fp fc1_w  = (fp)d_in[10];
    fp fc1_b  = (fp)d_in[11];
    fp fc2_w  = (fp)d_in[12];
    fp fc2_b  = (fp)d_in[13];
    float* out = (float*)d_out;

    float* ws = (float*)d_ws;
    float* h  = ws;                                                    // (spare)
    unsigned short* xn = (unsigned short*)(h + (size_t)TOKS * CDIM);   // (spare)
    unsigned short* hn = xn + (size_t)TOKS * CDIM;                     // (spare)
    float* qb = (float*)(hn + (size_t)TOKS * CDIM);
    unsigned short* kvb   = (unsigned short*)(qb + (size_t)TOKS * CDIM);
    unsigned short* attnb = kvb + (size_t)TOKS * 256;
    unsigned short* wt    = attnb + (size_t)TOKS * CDIM;

    unsigned short* wt0 = wt;            // qkv  [384][128]
    unsigned short* wt1 = wt + 49152;    // proj frag-major
    unsigned short* wt2 = wt + 65536;    // fc1  frag-major
    unsigned short* wt3 = wt + 131072;   // fc2  frag-major

    prep<<<768, 256, 0, stream>>>(qkv_w, proj_w, fc1_w, fc2_w, wt);
    k1_mfma<<<dim3(TOKS / 128, 6), 256, 0, stream>>>(x, ln1_g, ln1_b, wt0, qkv_b, qb, kvb);
    k2_attn<<<TOKS / 64, 512, 0, stream>>>(qb, kvb, rpb, attnb);
    kpm4<<<TOKS / 32, 512, 0, stream>>>(attnb, x, wt1, proj_b, ln2_g, ln2_b,
                                        wt2, fc1_b, wt3, fc2_b, out);
}